// Round 1
// baseline (185.410 us; speedup 1.0000x reference)
//
#include <hip/hip_runtime.h>
#include <hip/hip_fp16.h>

#define BB 8
#define NN 8192
#define SS 2048
#define CC 256
#define KNN 8
#define TOPM 10       // per-list candidate count (top-8 + margin)
#define NLIST 4       // 4 lists per query (one per 16-lane MFMA row group)
#define QPB 64        // queries per block (16 per wave x 4 waves)
#define MSTRIDE 41    // mbuf per-query stride (u32s): 41 mod 32 = 9 -> conflict-free
#define FSTR 12       // feat LDS stride in halves (24 B): banks 6s mod 32 -> ~4-way

#define UMIN(a, b) __builtin_elementwise_min(a, b)
#define UMAX(a, b) __builtin_elementwise_max(a, b)
#define UMIN3(a, b, c) UMIN(UMIN(a, b), c)

typedef short bf16x8_t __attribute__((ext_vector_type(8)));   // 8 bf16 = 4 VGPR
typedef float f32x4_t __attribute__((ext_vector_type(4)));

__device__ __forceinline__ unsigned pack_h2(float a, float b) {
    __half2 h = __halves2half2(__float2half_rn(a), __float2half_rn(b));
    return *reinterpret_cast<unsigned*>(&h);
}
__device__ __forceinline__ float2 unpack_h2(unsigned u) {
    __half2 h = *reinterpret_cast<__half2*>(&u);
    return __half22float2(h);
}

// f32 -> bf16 (RNE) and back, bit-level
__device__ __forceinline__ unsigned short f2bf(float f) {
    unsigned u = __float_as_uint(f);
    u += 0x7FFFu + ((u >> 16) & 1u);
    return (unsigned short)(u >> 16);
}
__device__ __forceinline__ float bf2f(unsigned short h) {
    return __uint_as_float((unsigned)h << 16);
}

// merge a sorted pair (ca,cb unordered) into ascending top-10 list (proven net)
__device__ __forceinline__ void ins2(unsigned k1[TOPM], unsigned ca, unsigned cb) {
    unsigned lo = UMIN(ca, cb), hi = UMAX(ca, cb);
#pragma unroll
    for (int j = TOPM - 1; j >= 2; --j)
        k1[j] = UMIN3(k1[j], UMAX(k1[j - 1], lo), UMAX(k1[j - 2], hi));
    k1[1] = UMIN3(k1[1], UMAX(k1[0], lo), hi);
    k1[0] = UMIN(k1[0], lo);
}

__device__ __forceinline__ void ins_step(unsigned k1[TOPM], f32x4_t d, unsigned sbase) {
    // key = truncated distance bits | point index (11 bits); d > 0 guaranteed (bias)
    unsigned c0 = (__float_as_uint(d[0]) & 0xFFFFF800u) | sbase;
    unsigned c1 = (__float_as_uint(d[1]) & 0xFFFFF800u) | (sbase + 1u);
    unsigned c2 = (__float_as_uint(d[2]) & 0xFFFFF800u) | (sbase + 2u);
    unsigned c3 = (__float_as_uint(d[3]) & 0xFFFFF800u) | (sbase + 3u);
    ins2(k1, c0, c1);
    ins2(k1, c2, c3);
}

// ---------------- Kernel A: MFMA split-bf16 distances + top-10 + f64 re-rank
// d~ = |p|^2 - 2 q.p + (|q|^2 + 2^-4), computed by v_mfma_f32_16x16x32_bf16 with
// hi/lo bf16 splits (error ~1e-4 << key truncation already tolerated by margin).
// Each lane owns one query (D col = lane&15) and gets 4 point-distances per MFMA
// (rows 4*(lane>>4)+reg). 128 steps -> per-lane top-10 over a 512-pt subset;
// 4 lists/query -> identical 40-candidate f64 re-rank phase as before.
__global__ __launch_bounds__(256, 2) void knn_kernel(
    const float* __restrict__ xyz,   // [B,3,N]
    const float* __restrict__ sxyz,  // [B,3,S]
    unsigned* __restrict__ out_pk)   // [B,N,8] packed (f16 w | idx)
{
    // tile0 [SS*8] = dims k0..7 | 16B zero pad | tile1 [SS*8] = dims k8..15
    // pad skews tile1 banks by 4 dwords -> g0/g1 reads hit disjoint bank quads.
    __shared__ unsigned short tile[SS * 16 + 8];      // 64 KB + 16 B
    __shared__ unsigned mbuf[QPB * MSTRIDE];          // 10.25 KB

    const int b    = blockIdx.x >> 7;                 // 128 blocks per batch
    const int q0   = (blockIdx.x & 127) * QPB;
    const int tid  = threadIdx.x;
    const int wave = tid >> 6;
    const int lane = tid & 63;
    const int g    = lane >> 4;                       // MFMA row group / list id
    const int qi   = lane & 15;                       // query-in-wave / A-row

    const float* sb = sxyz + (long)b * 3 * SS;

    // ---- stage split-bf16 point tiles -------------------------------------
#pragma unroll
    for (int i = 0; i < SS / 256; ++i) {
        int s = i * 256 + tid;
        float px = sb[s], py = sb[SS + s], pz = sb[2 * SS + s];
        unsigned short xh = f2bf(px); unsigned short xl = f2bf(px - bf2f(xh));
        unsigned short yh = f2bf(py); unsigned short yl = f2bf(py - bf2f(yh));
        unsigned short zh = f2bf(pz); unsigned short zl = f2bf(pz - bf2f(zh));
        float pn = fmaf(px, px, fmaf(py, py, pz * pz));
        unsigned short nh = f2bf(pn); unsigned short nl = f2bf(pn - bf2f(nh));
        const unsigned ONE = 0x3F80u;
        // k0..7  = [xh, xl, xh, yh, yl, yh, zh, zl]
        uint4 t0 = make_uint4((unsigned)xh | ((unsigned)xl << 16),
                              (unsigned)xh | ((unsigned)yh << 16),
                              (unsigned)yl | ((unsigned)yh << 16),
                              (unsigned)zh | ((unsigned)zl << 16));
        // k8..15 = [zh, nh, nl, 1, 1, 0, 0, 0]
        uint4 t1 = make_uint4((unsigned)zh | ((unsigned)nh << 16),
                              (unsigned)nl | (ONE << 16),
                              ONE, 0u);
        *(uint4*)&tile[s * 8] = t0;
        *(uint4*)&tile[SS * 8 + 8 + s * 8] = t1;
    }
    if (tid == 0) *(uint4*)&tile[SS * 8] = make_uint4(0u, 0u, 0u, 0u);  // zero frag for g>=2

    // ---- per-lane query B-fragment (col = lane&15, k = 8*g + e) ------------
    const float* xb = xyz + (long)b * 3 * NN;
    const int nq = q0 + wave * 16 + qi;
    const float qx = xb[nq], qy = xb[NN + nq], qz = xb[2 * NN + nq];

    bf16x8_t qf = (bf16x8_t)0;
    {
        unsigned short xh = f2bf(qx); float xhf = bf2f(xh);
        unsigned short yh = f2bf(qy); float yhf = bf2f(yh);
        unsigned short zh = f2bf(qz); float zhf = bf2f(zh);
        unsigned short xh2 = f2bf(-2.f * xhf), xl2 = f2bf(-2.f * (qx - xhf));
        unsigned short yh2 = f2bf(-2.f * yhf), yl2 = f2bf(-2.f * (qy - yhf));
        unsigned short zh2 = f2bf(-2.f * zhf), zl2 = f2bf(-2.f * (qz - zhf));
        float qn = fmaf(qx, qx, fmaf(qy, qy, qz * qz)) + 0.0625f;  // bias keeps d>0
        unsigned short nh = f2bf(qn); unsigned short nl = f2bf(qn - bf2f(nh));
        const short ONE = (short)0x3F80;
        if (g == 0) {
            qf[0] = (short)xh2; qf[1] = (short)xh2; qf[2] = (short)xl2;
            qf[3] = (short)yh2; qf[4] = (short)yh2; qf[5] = (short)yl2;
            qf[6] = (short)zh2; qf[7] = (short)zh2;
        } else if (g == 1) {
            qf[0] = (short)zl2; qf[1] = ONE; qf[2] = ONE;
            qf[3] = (short)nh;  qf[4] = (short)nl;
        } // g>=2: zero fragment (k16..31 unused)
    }
    __syncthreads();

    // ---- phase 1: 128 MFMA steps, 1-deep software pipeline ----------------
    const unsigned short* abase;
    int astep;
    if (g == 0)      { abase = &tile[qi * 8];               astep = 128; }
    else if (g == 1) { abase = &tile[SS * 8 + 8 + qi * 8];  astep = 128; }
    else             { abase = &tile[SS * 8];               astep = 0;   }  // 16B zeros

    unsigned k1[TOPM];
#pragma unroll
    for (int j = 0; j < TOPM; ++j) k1[j] = 0xFFFFFFFFu;

    const f32x4_t zacc = {0.f, 0.f, 0.f, 0.f};
    const unsigned ib4 = (unsigned)(g * 4);

    bf16x8_t af = *(const bf16x8_t*)abase; abase += astep;
    f32x4_t dc = __builtin_amdgcn_mfma_f32_16x16x32_bf16(af, qf, zacc, 0, 0, 0);

#pragma unroll 2
    for (int step = 0; step < 127; ++step) {
        bf16x8_t an = *(const bf16x8_t*)abase; abase += astep;
        f32x4_t dn = __builtin_amdgcn_mfma_f32_16x16x32_bf16(an, qf, zacc, 0, 0, 0);
        ins_step(k1, dc, ib4 + (unsigned)(step * 16));
        dc = dn;
    }
    ins_step(k1, dc, ib4 + (unsigned)(127 * 16));

    {
        unsigned* m1 = &mbuf[(wave * 16 + qi) * MSTRIDE + g * TOPM];
#pragma unroll
        for (int j = 0; j < TOPM; ++j) m1[j] = k1[j];
    }
    __syncthreads();

    // ---- phase 2: one thread per query, f64 re-rank of 40 candidates ------
    if (tid < QPB) {
        const int n2 = q0 + tid;
        const double dqx = (double)xb[n2], dqy = (double)xb[NN + n2], dqz = (double)xb[2 * NN + n2];
        const unsigned* ml = &mbuf[tid * MSTRIDE];

        unsigned long long top[KNN];
#pragma unroll
        for (int j = 0; j < KNN; ++j) top[j] = ~0ull;

#pragma unroll 4
        for (int j = 0; j < NLIST * TOPM; ++j) {
            unsigned key = ml[j];
            int s = key & 0x7FF;
            float px = sb[s], py = sb[SS + s], pz = sb[2 * SS + s];  // L2-hot (24 KB/batch)
            double ex = (double)px - dqx;
            double ey = (double)py - dqy;
            double ez = (double)pz - dqz;
            double dd = ex * ex + ey * ey + ez * ez;
            unsigned long long c =
                (((unsigned long long)__double_as_longlong(dd)) & ~0x7FFull) | (unsigned long long)s;
#pragma unroll
            for (int jj = KNN - 1; jj >= 1; --jj)
                top[jj] = UMIN(UMAX(top[jj - 1], c), top[jj]);
            top[0] = UMIN(top[0], c);
        }

        // IDW weights (f32, identical math to passing epilogue)
        const float fqx = xb[n2], fqy = xb[NN + n2], fqz = xb[2 * NN + n2];
        int   id[KNN];
        float inv[KNN];
        float ssum = 0.f;
#pragma unroll
        for (int k = 0; k < KNN; ++k) {
            id[k] = (int)(top[k] & 0x7FFull);
            float px = sb[id[k]], py = sb[SS + id[k]], pz = sb[2 * SS + id[k]];
            float dx = px - fqx, dy = py - fqy, dz = pz - fqz;
            float dv = sqrtf(dx * dx + dy * dy + dz * dz);
            dv = fmaxf(dv, 1e-10f);
            inv[k] = 1.0f / dv;
            ssum += inv[k];
        }
        const float rs = 1.0f / ssum;
        const long base = ((long)b * NN + n2) * KNN;
#pragma unroll
        for (int k = 0; k < KNN; ++k) {
            unsigned hw = (unsigned)__half_as_ushort(__float2half_rn(inv[k] * rs));
            out_pk[base + k] = (hw << 16) | (unsigned)id[k];
        }
    }
}

// ---------------- Kernel C: LDS-resident feature gather (UNCHANGED) ---------
__global__ __launch_bounds__(256, 2) void accum_kernel(
    const float*    __restrict__ sf,   // [B,C,S]
    const unsigned* __restrict__ pk,   // [B,N,8] packed (f16 w | idx)
    float* __restrict__ out)           // [B,C,N]
{
    __shared__ unsigned short feat[SS * FSTR];   // 48 KB

    const int blk  = blockIdx.x;
    const int b    = blk >> 6;             // 64 blocks per batch
    const int ct   = (blk >> 1) & 31;      // channel tile 0..31
    const int half = blk & 1;              // n half
    const int t    = threadIdx.x;
    const int c0   = ct * 8;

    // ---- stage: thread <-> point s, 8 channels each, cvt f32->f16 ----
    const float* sfb = sf + ((long)b * CC + c0) * SS;
#pragma unroll
    for (int i = 0; i < SS / 256; ++i) {
        int s = i * 256 + t;
        float f[8];
#pragma unroll
        for (int c = 0; c < 8; ++c) f[c] = sfb[(long)c * SS + s];
        uint2 w0 = make_uint2(pack_h2(f[0], f[1]), pack_h2(f[2], f[3]));
        uint2 w1 = make_uint2(pack_h2(f[4], f[5]), pack_h2(f[6], f[7]));
        *(uint2*)&feat[s * FSTR]     = w0;     // ds_write_b64
        *(uint2*)&feat[s * FSTR + 4] = w1;
    }
    __syncthreads();

    const unsigned* pkb = pk + ((long)b * NN + half * 4096) * KNN;
    float* outb = out + ((long)b * CC + c0) * NN + half * 4096;

    for (int it = 0; it < 4096 / 256; ++it) {
        const int nrel = it * 256 + t;
        const uint4 pa = *(const uint4*)(pkb + (long)nrel * KNN);
        const uint4 pb = *(const uint4*)(pkb + (long)nrel * KNN + 4);
        const unsigned pks[8] = {pa.x, pa.y, pa.z, pa.w, pb.x, pb.y, pb.z, pb.w};

        float acc[8];
#pragma unroll
        for (int c = 0; c < 8; ++c) acc[c] = 0.f;

#pragma unroll
        for (int k = 0; k < KNN; ++k) {
            const unsigned p = pks[k];
            const int id = p & 0x7FF;
            const float w = __half2float(__ushort_as_half((unsigned short)(p >> 16)));
            const unsigned short* fp = &feat[id * FSTR];
            uint2 A = *(const uint2*)fp;         // ds_read_b64: ch 0-3
            uint2 B = *(const uint2*)(fp + 4);   // ds_read_b64: ch 4-7
            float2 f0 = unpack_h2(A.x), f1 = unpack_h2(A.y);
            float2 f2 = unpack_h2(B.x), f3 = unpack_h2(B.y);
            acc[0] = fmaf(w, f0.x, acc[0]);
            acc[1] = fmaf(w, f0.y, acc[1]);
            acc[2] = fmaf(w, f1.x, acc[2]);
            acc[3] = fmaf(w, f1.y, acc[3]);
            acc[4] = fmaf(w, f2.x, acc[4]);
            acc[5] = fmaf(w, f2.y, acc[5]);
            acc[6] = fmaf(w, f3.x, acc[6]);
            acc[7] = fmaf(w, f3.y, acc[7]);
        }

#pragma unroll
        for (int c = 0; c < 8; ++c)
            outb[(long)c * NN + nrel] = acc[c];   // coalesced per channel row
    }
}

extern "C" void kernel_launch(void* const* d_in, const int* in_sizes, int n_in,
                              void* d_out, int out_size, void* d_ws, size_t ws_size,
                              hipStream_t stream) {
    const float* xyz  = (const float*)d_in[0];   // [8,3,8192]
    const float* sxyz = (const float*)d_in[1];   // [8,3,2048]
    const float* sf   = (const float*)d_in[2];   // [8,256,2048]
    float* out = (float*)d_out;                  // [8,256,8192]

    unsigned* pkbuf = (unsigned*)d_ws;           // 2 MB packed (f16 w | idx)

    knn_kernel<<<dim3(BB * NN / QPB), dim3(256), 0, stream>>>(xyz, sxyz, pkbuf);
    accum_kernel<<<dim3(BB * 32 * 2), dim3(256), 0, stream>>>(sf, pkbuf, out);
}

// Round 2
// 175.638 us; speedup vs baseline: 1.0556x; 1.0556x over previous
//
#include <hip/hip_runtime.h>
#include <hip/hip_fp16.h>

#define BB 8
#define NN 8192
#define SS 2048
#define CC 256
#define KNN 8
#define TOPM 10       // per-list candidate count (top-8 + margin)
#define NLIST 4       // 4 lists per query (one per 16-lane MFMA row group)
#define QPB 64        // queries per block (16 per wave x 4 waves)
#define MSTRIDE 41    // mbuf per-query stride (u32s): 41 mod 32 = 9 -> conflict-free
#define FSTR 12       // feat LDS stride in halves (24 B): banks 6s mod 32 -> ~4-way

#define UMIN(a, b) __builtin_elementwise_min(a, b)
#define UMAX(a, b) __builtin_elementwise_max(a, b)
#define UMIN3(a, b, c) UMIN(UMIN(a, b), c)

typedef short bf16x8_t __attribute__((ext_vector_type(8)));   // 8 bf16 = 4 VGPR
typedef float f32x4_t __attribute__((ext_vector_type(4)));

__device__ __forceinline__ unsigned pack_h2(float a, float b) {
    __half2 h = __halves2half2(__float2half_rn(a), __float2half_rn(b));
    return *reinterpret_cast<unsigned*>(&h);
}
__device__ __forceinline__ float2 unpack_h2(unsigned u) {
    __half2 h = *reinterpret_cast<__half2*>(&u);
    return __half22float2(h);
}

// f32 -> bf16 (RNE) and back, bit-level
__device__ __forceinline__ unsigned short f2bf(float f) {
    unsigned u = __float_as_uint(f);
    u += 0x7FFFu + ((u >> 16) & 1u);
    return (unsigned short)(u >> 16);
}
__device__ __forceinline__ float bf2f(unsigned short h) {
    return __uint_as_float((unsigned)h << 16);
}

// merge an unordered pair (ca,cb) into ascending top-10 list (proven net)
__device__ __forceinline__ void ins2(unsigned k1[TOPM], unsigned ca, unsigned cb) {
    unsigned lo = UMIN(ca, cb), hi = UMAX(ca, cb);
#pragma unroll
    for (int j = TOPM - 1; j >= 2; --j)
        k1[j] = UMIN3(k1[j], UMAX(k1[j - 1], lo), UMAX(k1[j - 2], hi));
    k1[1] = UMIN3(k1[1], UMAX(k1[0], lo), hi);
    k1[0] = UMIN(k1[0], lo);
}

__device__ __forceinline__ void ins_step(unsigned k1[TOPM], f32x4_t d, unsigned sbase) {
    // key = truncated distance bits | point index (11 bits); d > 0 guaranteed (bias)
    unsigned c0 = (__float_as_uint(d[0]) & 0xFFFFF800u) | sbase;
    unsigned c1 = (__float_as_uint(d[1]) & 0xFFFFF800u) | (sbase + 1u);
    unsigned c2 = (__float_as_uint(d[2]) & 0xFFFFF800u) | (sbase + 2u);
    unsigned c3 = (__float_as_uint(d[3]) & 0xFFFFF800u) | (sbase + 3u);
    ins2(k1, c0, c1);
    ins2(k1, c2, c3);
}

// ---------------- Kernel P: build split-bf16 A-tiles in global (512 KB) -----
// Layout per batch: [2][SS][8] shorts. t0 = k0..7, t1 = k8..15 fragment rows,
// in exactly the order lane (qi, g) consumes them: row s, 16B per point.
__global__ __launch_bounds__(256) void prep_kernel(
    const float* __restrict__ sxyz,        // [B,3,S]
    unsigned short* __restrict__ gt)       // [B][2][SS][8]
{
    const int b = blockIdx.x;
    const int tid = threadIdx.x;
    const float* sb = sxyz + (long)b * 3 * SS;
    unsigned short* gb = gt + (long)b * 2 * SS * 8;
#pragma unroll
    for (int i = 0; i < SS / 256; ++i) {
        int s = i * 256 + tid;
        float px = sb[s], py = sb[SS + s], pz = sb[2 * SS + s];
        unsigned short xh = f2bf(px); unsigned short xl = f2bf(px - bf2f(xh));
        unsigned short yh = f2bf(py); unsigned short yl = f2bf(py - bf2f(yh));
        unsigned short zh = f2bf(pz); unsigned short zl = f2bf(pz - bf2f(zh));
        float pn = fmaf(px, px, fmaf(py, py, pz * pz));
        unsigned short nh = f2bf(pn); unsigned short nl = f2bf(pn - bf2f(nh));
        const unsigned ONE = 0x3F80u;
        // k0..7  = [xh, xl, xh, yh, yl, yh, zh, zl]
        uint4 t0 = make_uint4((unsigned)xh | ((unsigned)xl << 16),
                              (unsigned)xh | ((unsigned)yh << 16),
                              (unsigned)yl | ((unsigned)yh << 16),
                              (unsigned)zh | ((unsigned)zl << 16));
        // k8..15 = [zh, nh, nl, 1, 1, 0, 0, 0]
        uint4 t1 = make_uint4((unsigned)zh | ((unsigned)nh << 16),
                              (unsigned)nl | (ONE << 16),
                              ONE, 0u);
        *(uint4*)&gb[(long)s * 8] = t0;
        *(uint4*)&gb[((long)SS + s) * 8] = t1;
    }
}

// ---------------- Kernel A: MFMA distances, tiles read from global (L2-hot) -
// d~ = |p|^2 - 2 q.p + (|q|^2 + 2^-4) via v_mfma_f32_16x16x32_bf16, split-bf16.
// LDS = mbuf only (10.25 KB) -> 4 blocks/CU (grid-capped), 4 waves/SIMD.
// B-fragment is zero for k>=13, so g>=2 lanes load harmless finite data
// (uniform control flow, their A-slices multiply zero).
__global__ __launch_bounds__(256, 4) void knn_kernel(
    const float* __restrict__ xyz,         // [B,3,N]
    const float* __restrict__ sxyz,        // [B,3,S]
    const unsigned short* __restrict__ gt, // [B][2][SS][8] split-bf16 tiles
    unsigned* __restrict__ out_pk)         // [B,N,8] packed (f16 w | idx)
{
    __shared__ unsigned mbuf[QPB * MSTRIDE];          // 10.25 KB

    const int b    = blockIdx.x >> 7;                 // 128 blocks per batch
    const int q0   = (blockIdx.x & 127) * QPB;
    const int tid  = threadIdx.x;
    const int wave = tid >> 6;
    const int lane = tid & 63;
    const int g    = lane >> 4;                       // MFMA row group / list id
    const int qi   = lane & 15;                       // query-in-wave / A-row

    const float* sb = sxyz + (long)b * 3 * SS;
    const float* xb = xyz + (long)b * 3 * NN;

    // ---- per-lane query B-fragment (col = lane&15, k = 8*g + e) ------------
    const int nq = q0 + wave * 16 + qi;
    const float qx = xb[nq], qy = xb[NN + nq], qz = xb[2 * NN + nq];

    bf16x8_t qf = (bf16x8_t)0;
    {
        unsigned short xh = f2bf(qx); float xhf = bf2f(xh);
        unsigned short yh = f2bf(qy); float yhf = bf2f(yh);
        unsigned short zh = f2bf(qz); float zhf = bf2f(zh);
        unsigned short xh2 = f2bf(-2.f * xhf), xl2 = f2bf(-2.f * (qx - xhf));
        unsigned short yh2 = f2bf(-2.f * yhf), yl2 = f2bf(-2.f * (qy - yhf));
        unsigned short zh2 = f2bf(-2.f * zhf), zl2 = f2bf(-2.f * (qz - zhf));
        float qn = fmaf(qx, qx, fmaf(qy, qy, qz * qz)) + 0.0625f;  // bias keeps d>0
        unsigned short nh = f2bf(qn); unsigned short nl = f2bf(qn - bf2f(nh));
        const short ONE = (short)0x3F80;
        if (g == 0) {
            qf[0] = (short)xh2; qf[1] = (short)xh2; qf[2] = (short)xl2;
            qf[3] = (short)yh2; qf[4] = (short)yh2; qf[5] = (short)yl2;
            qf[6] = (short)zh2; qf[7] = (short)zh2;
        } else if (g == 1) {
            qf[0] = (short)zl2; qf[1] = ONE; qf[2] = ONE;
            qf[3] = (short)nh;  qf[4] = (short)nl;
        } // g>=2: zero fragment (k16..31 unused -> A-slices don't matter)
    }

    // ---- phase 1: 128 MFMA steps, depth-1 software pipeline ----------------
    // g even -> t0 rows, g odd -> t1 rows (g2/g3 duplicate g0/g1 addresses;
    // their products are zeroed by qf=0, data is finite so no NaN).
    const unsigned short* abase =
        gt + (long)b * 2 * SS * 8 + (long)(g & 1) * SS * 8 + qi * 8;

    unsigned k1[TOPM];
#pragma unroll
    for (int j = 0; j < TOPM; ++j) k1[j] = 0xFFFFFFFFu;

    const f32x4_t zacc = {0.f, 0.f, 0.f, 0.f};
    const unsigned ib4 = (unsigned)(g * 4);

    bf16x8_t af = *(const bf16x8_t*)abase; abase += 128;
    f32x4_t dc = __builtin_amdgcn_mfma_f32_16x16x32_bf16(af, qf, zacc, 0, 0, 0);

#pragma unroll 2
    for (int step = 0; step < 127; ++step) {
        bf16x8_t an = *(const bf16x8_t*)abase; abase += 128;
        f32x4_t dn = __builtin_amdgcn_mfma_f32_16x16x32_bf16(an, qf, zacc, 0, 0, 0);
        ins_step(k1, dc, ib4 + (unsigned)(step * 16));
        dc = dn;
    }
    ins_step(k1, dc, ib4 + (unsigned)(127 * 16));

    {
        unsigned* m1 = &mbuf[(wave * 16 + qi) * MSTRIDE + g * TOPM];
#pragma unroll
        for (int j = 0; j < TOPM; ++j) m1[j] = k1[j];
    }
    __syncthreads();

    // ---- phase 2: one thread per query, f64 re-rank of 40 candidates ------
    if (tid < QPB) {
        const int n2 = q0 + tid;
        const double dqx = (double)xb[n2], dqy = (double)xb[NN + n2], dqz = (double)xb[2 * NN + n2];
        const unsigned* ml = &mbuf[tid * MSTRIDE];

        unsigned long long top[KNN];
#pragma unroll
        for (int j = 0; j < KNN; ++j) top[j] = ~0ull;

#pragma unroll 4
        for (int j = 0; j < NLIST * TOPM; ++j) {
            unsigned key = ml[j];
            int s = key & 0x7FF;
            float px = sb[s], py = sb[SS + s], pz = sb[2 * SS + s];  // L2-hot (24 KB/batch)
            double ex = (double)px - dqx;
            double ey = (double)py - dqy;
            double ez = (double)pz - dqz;
            double dd = ex * ex + ey * ey + ez * ez;
            unsigned long long c =
                (((unsigned long long)__double_as_longlong(dd)) & ~0x7FFull) | (unsigned long long)s;
#pragma unroll
            for (int jj = KNN - 1; jj >= 1; --jj)
                top[jj] = UMIN(UMAX(top[jj - 1], c), top[jj]);
            top[0] = UMIN(top[0], c);
        }

        // IDW weights (f32, identical math to passing epilogue)
        const float fqx = xb[n2], fqy = xb[NN + n2], fqz = xb[2 * NN + n2];
        int   id[KNN];
        float inv[KNN];
        float ssum = 0.f;
#pragma unroll
        for (int k = 0; k < KNN; ++k) {
            id[k] = (int)(top[k] & 0x7FFull);
            float px = sb[id[k]], py = sb[SS + id[k]], pz = sb[2 * SS + id[k]];
            float dx = px - fqx, dy = py - fqy, dz = pz - fqz;
            float dv = sqrtf(dx * dx + dy * dy + dz * dz);
            dv = fmaxf(dv, 1e-10f);
            inv[k] = 1.0f / dv;
            ssum += inv[k];
        }
        const float rs = 1.0f / ssum;
        const long base = ((long)b * NN + n2) * KNN;
#pragma unroll
        for (int k = 0; k < KNN; ++k) {
            unsigned hw = (unsigned)__half_as_ushort(__float2half_rn(inv[k] * rs));
            out_pk[base + k] = (hw << 16) | (unsigned)id[k];
        }
    }
}

// ---------------- Kernel C: LDS-resident feature gather (UNCHANGED) ---------
__global__ __launch_bounds__(256, 2) void accum_kernel(
    const float*    __restrict__ sf,   // [B,C,S]
    const unsigned* __restrict__ pk,   // [B,N,8] packed (f16 w | idx)
    float* __restrict__ out)           // [B,C,N]
{
    __shared__ unsigned short feat[SS * FSTR];   // 48 KB

    const int blk  = blockIdx.x;
    const int b    = blk >> 6;             // 64 blocks per batch
    const int ct   = (blk >> 1) & 31;      // channel tile 0..31
    const int half = blk & 1;              // n half
    const int t    = threadIdx.x;
    const int c0   = ct * 8;

    // ---- stage: thread <-> point s, 8 channels each, cvt f32->f16 ----
    const float* sfb = sf + ((long)b * CC + c0) * SS;
#pragma unroll
    for (int i = 0; i < SS / 256; ++i) {
        int s = i * 256 + t;
        float f[8];
#pragma unroll
        for (int c = 0; c < 8; ++c) f[c] = sfb[(long)c * SS + s];
        uint2 w0 = make_uint2(pack_h2(f[0], f[1]), pack_h2(f[2], f[3]));
        uint2 w1 = make_uint2(pack_h2(f[4], f[5]), pack_h2(f[6], f[7]));
        *(uint2*)&feat[s * FSTR]     = w0;     // ds_write_b64
        *(uint2*)&feat[s * FSTR + 4] = w1;
    }
    __syncthreads();

    const unsigned* pkb = pk + ((long)b * NN + half * 4096) * KNN;
    float* outb = out + ((long)b * CC + c0) * NN + half * 4096;

    for (int it = 0; it < 4096 / 256; ++it) {
        const int nrel = it * 256 + t;
        const uint4 pa = *(const uint4*)(pkb + (long)nrel * KNN);
        const uint4 pb = *(const uint4*)(pkb + (long)nrel * KNN + 4);
        const unsigned pks[8] = {pa.x, pa.y, pa.z, pa.w, pb.x, pb.y, pb.z, pb.w};

        float acc[8];
#pragma unroll
        for (int c = 0; c < 8; ++c) acc[c] = 0.f;

#pragma unroll
        for (int k = 0; k < KNN; ++k) {
            const unsigned p = pks[k];
            const int id = p & 0x7FF;
            const float w = __half2float(__ushort_as_half((unsigned short)(p >> 16)));
            const unsigned short* fp = &feat[id * FSTR];
            uint2 A = *(const uint2*)fp;         // ds_read_b64: ch 0-3
            uint2 B = *(const uint2*)(fp + 4);   // ds_read_b64: ch 4-7
            float2 f0 = unpack_h2(A.x), f1 = unpack_h2(A.y);
            float2 f2 = unpack_h2(B.x), f3 = unpack_h2(B.y);
            acc[0] = fmaf(w, f0.x, acc[0]);
            acc[1] = fmaf(w, f0.y, acc[1]);
            acc[2] = fmaf(w, f1.x, acc[2]);
            acc[3] = fmaf(w, f1.y, acc[3]);
            acc[4] = fmaf(w, f2.x, acc[4]);
            acc[5] = fmaf(w, f2.y, acc[5]);
            acc[6] = fmaf(w, f3.x, acc[6]);
            acc[7] = fmaf(w, f3.y, acc[7]);
        }

#pragma unroll
        for (int c = 0; c < 8; ++c)
            outb[(long)c * NN + nrel] = acc[c];   // coalesced per channel row
    }
}

extern "C" void kernel_launch(void* const* d_in, const int* in_sizes, int n_in,
                              void* d_out, int out_size, void* d_ws, size_t ws_size,
                              hipStream_t stream) {
    const float* xyz  = (const float*)d_in[0];   // [8,3,8192]
    const float* sxyz = (const float*)d_in[1];   // [8,3,2048]
    const float* sf   = (const float*)d_in[2];   // [8,256,2048]
    float* out = (float*)d_out;                  // [8,256,8192]

    unsigned* pkbuf = (unsigned*)d_ws;                              // 2 MB packed
    unsigned short* gtile = (unsigned short*)((char*)d_ws + (size_t)BB * NN * KNN * 4); // +512 KB

    prep_kernel<<<dim3(BB), dim3(256), 0, stream>>>(sxyz, gtile);
    knn_kernel<<<dim3(BB * NN / QPB), dim3(256), 0, stream>>>(xyz, sxyz, gtile, pkbuf);
    accum_kernel<<<dim3(BB * 32 * 2), dim3(256), 0, stream>>>(sf, pkbuf, out);
}